// Round 7
// baseline (274.958 us; speedup 1.0000x reference)
//
#include <hip/hip_runtime.h>
#include <math.h>

#define EMB_DIM 512
#define N_Q 8
#define GAMMA_F 12.0f
#define REPEAT 4   // measurement: replicate the streaming pass to force the
                   // kernel above the ~71us poison fills into rocprof top-5.
                   // Identical work each pass; output rewritten identically.

// ---------------------------------------------------------------------------
// RotatE scoring, barrier-free (R5 structure), 4x repeated for profiling.
// Block = 4 waves; wave w owns queries {2w,2w+1} over the FULL entity row;
// 4 waves/block stream the same rows. No LDS, no barriers in the loop.
// Per-lane q state: 32 floats. Depth-1 register prefetch.
// ---------------------------------------------------------------------------

__device__ __forceinline__ void rot4(const float4 reh, const float4 imh,
                                     const float4 ph, float scale,
                                     float4* qr, float4* qi)
{
    float s, c;
    __sincosf(ph.x * scale, &s, &c); qr->x = reh.x * c - imh.x * s; qi->x = reh.x * s + imh.x * c;
    __sincosf(ph.y * scale, &s, &c); qr->y = reh.y * c - imh.y * s; qi->y = reh.y * s + imh.y * c;
    __sincosf(ph.z * scale, &s, &c); qr->z = reh.z * c - imh.z * s; qi->z = reh.z * s + imh.z * c;
    __sincosf(ph.w * scale, &s, &c); qr->w = reh.w * c - imh.w * s; qi->w = reh.w * s + imh.w * c;
}

#define ACC4(qr4, qi4, er4, ei4, s) do {                                          \
    float dx_, dy_;                                                               \
    dx_ = (qr4).x - (er4).x; dy_ = (qi4).x - (ei4).x; s += __builtin_amdgcn_sqrtf(fmaf(dx_, dx_, dy_ * dy_)); \
    dx_ = (qr4).y - (er4).y; dy_ = (qi4).y - (ei4).y; s += __builtin_amdgcn_sqrtf(fmaf(dx_, dx_, dy_ * dy_)); \
    dx_ = (qr4).z - (er4).z; dy_ = (qi4).z - (ei4).z; s += __builtin_amdgcn_sqrtf(fmaf(dx_, dx_, dy_ * dy_)); \
    dx_ = (qr4).w - (er4).w; dy_ = (qi4).w - (ei4).w; s += __builtin_amdgcn_sqrtf(fmaf(dx_, dx_, dy_ * dy_)); \
} while (0)

__global__ __launch_bounds__(256, 4) void rotate_fused_kernel(
    const int* __restrict__ all_h,
    const int* __restrict__ all_r,
    const float* __restrict__ eemb,
    const float* __restrict__ remb,
    float* __restrict__ out,
    int N)
{
    const int tid  = threadIdx.x;
    const int lane = tid & 63;
    const int wid  = tid >> 6;
    const int b0   = wid << 1;                 // this wave's queries: b0, b0+1

    const float SCALE = (float)(M_PI * (double)EMB_DIM / 14.0);

    // ---- init: rotated query fragments, strictly in registers ----
    float4 qr_lo[2], qr_hi[2], qi_lo[2], qi_hi[2];
    #pragma unroll
    for (int qq = 0; qq < 2; ++qq) {
        int b = b0 + qq;
        int h = all_h[b];
        int r = all_r[b];
        const float* hrow = eemb + (size_t)h * (2 * EMB_DIM);
        const float* rrow = remb + (size_t)r * EMB_DIM;
        const int dlo = 4 * lane, dhi = 256 + 4 * lane;
        float4 reh, imh, ph;
        reh = *(const float4*)(hrow + dlo);
        imh = *(const float4*)(hrow + EMB_DIM + dlo);
        ph  = *(const float4*)(rrow + dlo);
        rot4(reh, imh, ph, SCALE, &qr_lo[qq], &qi_lo[qq]);
        reh = *(const float4*)(hrow + dhi);
        imh = *(const float4*)(hrow + EMB_DIM + dhi);
        ph  = *(const float4*)(rrow + dhi);
        rot4(reh, imh, ph, SCALE, &qr_hi[qq], &qi_hi[qq]);
    }

    const int stride = gridDim.x;
    const float* bp = eemb + 4 * lane;

    #pragma clang loop unroll(disable)
    for (int rep = 0; rep < REPEAT; ++rep) {
        int n = blockIdx.x;
        if (n >= N) break;

        float4 c0, c1, c2, c3;
        {
            const float* p = bp + (size_t)n * (2 * EMB_DIM);
            c0 = *(const float4*)(p);
            c1 = *(const float4*)(p + 256);
            c2 = *(const float4*)(p + 512);
            c3 = *(const float4*)(p + 768);
        }

        while (true) {
            const int n2 = n + stride;
            float4 p0, p1, p2, p3;
            {
                const int nc = (n2 < N) ? n2 : 0;
                const float* p = bp + (size_t)nc * (2 * EMB_DIM);
                p0 = *(const float4*)(p);
                p1 = *(const float4*)(p + 256);
                p2 = *(const float4*)(p + 512);
                p3 = *(const float4*)(p + 768);
            }

            float s0 = 0.f, s1 = 0.f;
            ACC4(qr_lo[0], qi_lo[0], c0, c2, s0);
            ACC4(qr_hi[0], qi_hi[0], c1, c3, s0);
            ACC4(qr_lo[1], qi_lo[1], c0, c2, s1);
            ACC4(qr_hi[1], qi_hi[1], c1, c3, s1);

            // transposing butterfly: even lanes carry b0, odd carry b0+1
            const bool po = lane & 1;
            float x = po ? s1 : s0;
            float z = po ? s0 : s1;
            x += __shfl_xor(z, 1);
            x += __shfl_xor(x, 2);
            x += __shfl_xor(x, 4);
            x += __shfl_xor(x, 8);
            x += __shfl_xor(x, 16);
            x += __shfl_xor(x, 32);
            if (lane < 2) out[(size_t)(b0 + lane) * N + n] = GAMMA_F - x;

            if (n2 >= N) break;
            n = n2;
            c0 = p0; c1 = p1; c2 = p2; c3 = p3;
        }
    }
}

extern "C" void kernel_launch(void* const* d_in, const int* in_sizes, int n_in,
                              void* d_out, int out_size, void* d_ws, size_t ws_size,
                              hipStream_t stream) {
    const int*   all_h = (const int*)d_in[0];
    const int*   all_r = (const int*)d_in[1];
    const float* eemb  = (const float*)d_in[2];
    const float* remb  = (const float*)d_in[3];
    float* out = (float*)d_out;

    int N = in_sizes[2] / (2 * EMB_DIM);   // 30000

    rotate_fused_kernel<<<1024, 256, 0, stream>>>(all_h, all_r, eemb, remb, out, N);
}

// Round 8
// 185.484 us; speedup vs baseline: 1.4824x; 1.4824x over previous
//
#include <hip/hip_runtime.h>
#include <math.h>

#define EMB_DIM 512
#define GAMMA_F 12.0f

typedef float v2f __attribute__((ext_vector_type(2)));

// ---------------------------------------------------------------------------
// RotatE scoring, packed-FP32 version.
//
// R7 measurement (4x replicated pass): VALUBusy 70-75%, HBM 24% -> the kernel
// is VALU-ISSUE bound, not memory bound. This version keeps the R5 barrier-
// free structure (block = 4 waves; wave w owns queries {2w,2w+1} over the
// full row; no LDS, no __syncthreads; depth-1 prefetch) but rewrites the
// element math on float2 ext-vectors so the backend emits v_pk_add_f32 /
// v_pk_mul_f32 / v_pk_fma_f32 (2 FP32 ops per issue slot on gfx950):
//   per query-iteration: 16 pk + 8 v_sqrt + 4 pk-acc   (was 40 scalar + 8 sqrt)
// v_sqrt_f32 (transcendental, 1/4-1/8 rate) is irreducible: 122.9M of them.
// ---------------------------------------------------------------------------

__device__ __forceinline__ v2f sqrt2(v2f t) {
    v2f r;
    r.x = __builtin_amdgcn_sqrtf(t.x);
    r.y = __builtin_amdgcn_sqrtf(t.y);
    return r;
}

__device__ __forceinline__ void rot4(const float4 reh, const float4 imh,
                                     const float4 ph, float scale,
                                     float4* qr, float4* qi)
{
    float s, c;
    __sincosf(ph.x * scale, &s, &c); qr->x = reh.x * c - imh.x * s; qi->x = reh.x * s + imh.x * c;
    __sincosf(ph.y * scale, &s, &c); qr->y = reh.y * c - imh.y * s; qi->y = reh.y * s + imh.y * c;
    __sincosf(ph.z * scale, &s, &c); qr->z = reh.z * c - imh.z * s; qi->z = reh.z * s + imh.z * c;
    __sincosf(ph.w * scale, &s, &c); qr->w = reh.w * c - imh.w * s; qi->w = reh.w * s + imh.w * c;
}

// one query, one d-chunk (2 complex dims, packed): 4 pk + 2 sqrt + 1 pk-acc
#define ACC2(QR, QI, ER, EI, ACC) do {                       \
    v2f d_ = (QR) - (ER);                                    \
    v2f e_ = (QI) - (EI);                                    \
    v2f t_ = d_ * d_;                                        \
    t_ = __builtin_elementwise_fma(e_, e_, t_);              \
    (ACC) += sqrt2(t_);                                      \
} while (0)

__global__ __launch_bounds__(256, 4) void rotate_fused_kernel(
    const int* __restrict__ all_h,
    const int* __restrict__ all_r,
    const float* __restrict__ eemb,
    const float* __restrict__ remb,
    float* __restrict__ out,
    int N)
{
    const int tid  = threadIdx.x;
    const int lane = tid & 63;
    const int wid  = tid >> 6;
    const int b0   = wid << 1;                 // this wave's queries: b0, b0+1

    const float SCALE = (float)(M_PI * (double)EMB_DIM / 14.0);

    // ---- init: rotated query fragments in registers (32 floats) ----
    float4 qr_lo[2], qr_hi[2], qi_lo[2], qi_hi[2];
    #pragma unroll
    for (int qq = 0; qq < 2; ++qq) {
        int b = b0 + qq;
        int h = all_h[b];
        int r = all_r[b];
        const float* hrow = eemb + (size_t)h * (2 * EMB_DIM);
        const float* rrow = remb + (size_t)r * EMB_DIM;
        const int dlo = 4 * lane, dhi = 256 + 4 * lane;
        float4 reh, imh, ph;
        reh = *(const float4*)(hrow + dlo);
        imh = *(const float4*)(hrow + EMB_DIM + dlo);
        ph  = *(const float4*)(rrow + dlo);
        rot4(reh, imh, ph, SCALE, &qr_lo[qq], &qi_lo[qq]);
        reh = *(const float4*)(hrow + dhi);
        imh = *(const float4*)(hrow + EMB_DIM + dhi);
        ph  = *(const float4*)(rrow + dhi);
        rot4(reh, imh, ph, SCALE, &qr_hi[qq], &qi_hi[qq]);
    }

    // packed views of the query fragments: Q*[query][chunk0..3]
    v2f Qr[2][4], Qi[2][4];
    #pragma unroll
    for (int qq = 0; qq < 2; ++qq) {
        Qr[qq][0] = (v2f){qr_lo[qq].x, qr_lo[qq].y};
        Qr[qq][1] = (v2f){qr_lo[qq].z, qr_lo[qq].w};
        Qr[qq][2] = (v2f){qr_hi[qq].x, qr_hi[qq].y};
        Qr[qq][3] = (v2f){qr_hi[qq].z, qr_hi[qq].w};
        Qi[qq][0] = (v2f){qi_lo[qq].x, qi_lo[qq].y};
        Qi[qq][1] = (v2f){qi_lo[qq].z, qi_lo[qq].w};
        Qi[qq][2] = (v2f){qi_hi[qq].x, qi_hi[qq].y};
        Qi[qq][3] = (v2f){qi_hi[qq].z, qi_hi[qq].w};
    }

    // ---- stream entities, depth-1 register prefetch, no barriers ----
    const int stride = gridDim.x;
    int n = blockIdx.x;
    if (n >= N) return;

    const float* bp = eemb + 4 * lane;   // row*1024 + {re_lo 0, re_hi 256, im_lo 512, im_hi 768}

    float4 c0, c1, c2, c3;
    {
        const float* p = bp + (size_t)n * (2 * EMB_DIM);
        c0 = *(const float4*)(p);
        c1 = *(const float4*)(p + 256);
        c2 = *(const float4*)(p + 512);
        c3 = *(const float4*)(p + 768);
    }

    while (true) {
        const int n2 = n + stride;
        float4 p0, p1, p2, p3;
        {
            const int nc = (n2 < N) ? n2 : 0;
            const float* p = bp + (size_t)nc * (2 * EMB_DIM);
            p0 = *(const float4*)(p);
            p1 = *(const float4*)(p + 256);
            p2 = *(const float4*)(p + 512);
            p3 = *(const float4*)(p + 768);
        }

        // packed row chunks: re {c0,c1}, im {c2,c3}
        v2f er0 = (v2f){c0.x, c0.y}, er1 = (v2f){c0.z, c0.w};
        v2f er2 = (v2f){c1.x, c1.y}, er3 = (v2f){c1.z, c1.w};
        v2f ei0 = (v2f){c2.x, c2.y}, ei1 = (v2f){c2.z, c2.w};
        v2f ei2 = (v2f){c3.x, c3.y}, ei3 = (v2f){c3.z, c3.w};

        v2f a0 = (v2f){0.f, 0.f}, a1 = (v2f){0.f, 0.f};
        ACC2(Qr[0][0], Qi[0][0], er0, ei0, a0);
        ACC2(Qr[0][1], Qi[0][1], er1, ei1, a0);
        ACC2(Qr[0][2], Qi[0][2], er2, ei2, a0);
        ACC2(Qr[0][3], Qi[0][3], er3, ei3, a0);
        ACC2(Qr[1][0], Qi[1][0], er0, ei0, a1);
        ACC2(Qr[1][1], Qi[1][1], er1, ei1, a1);
        ACC2(Qr[1][2], Qi[1][2], er2, ei2, a1);
        ACC2(Qr[1][3], Qi[1][3], er3, ei3, a1);

        float s0 = a0.x + a0.y;
        float s1 = a1.x + a1.y;

        // transposing butterfly: even lanes carry query b0, odd carry b0+1
        const bool po = lane & 1;
        float x = po ? s1 : s0;
        float z = po ? s0 : s1;
        x += __shfl_xor(z, 1);
        x += __shfl_xor(x, 2);
        x += __shfl_xor(x, 4);
        x += __shfl_xor(x, 8);
        x += __shfl_xor(x, 16);
        x += __shfl_xor(x, 32);
        if (lane < 2) out[(size_t)(b0 + lane) * N + n] = GAMMA_F - x;

        if (n2 >= N) break;
        n = n2;
        c0 = p0; c1 = p1; c2 = p2; c3 = p3;
    }
}

extern "C" void kernel_launch(void* const* d_in, const int* in_sizes, int n_in,
                              void* d_out, int out_size, void* d_ws, size_t ws_size,
                              hipStream_t stream) {
    const int*   all_h = (const int*)d_in[0];
    const int*   all_r = (const int*)d_in[1];
    const float* eemb  = (const float*)d_in[2];
    const float* remb  = (const float*)d_in[3];
    float* out = (float*)d_out;

    int N = in_sizes[2] / (2 * EMB_DIM);   // 30000

    // 1024 blocks = 4 blocks/CU (16 waves/CU); 4 waves of a block share rows.
    rotate_fused_kernel<<<1024, 256, 0, stream>>>(all_h, all_r, eemb, remb, out, N);
}